// Round 3
// baseline (212.464 us; speedup 1.0000x reference)
//
#include <hip/hip_runtime.h>
#include <hip/hip_bf16.h>

// CTC batch cost — split-phase, LINEAR-domain f64, FORWARD+BACKWARD meet in
// the middle: 128 sequential iterations instead of 255.
//   P = sum_s alpha_127[s] * beta_127[s]
// Forward: lane i holds alpha[2i] (lo), alpha[2i+1] (hi).
// Backward: lane i holds beta[2i+1] (a), beta[2i+2] (b); beta[0] in lane 32's a.
// B=1024, T=256, C=128, L=32, S=65, blank=127.
//
// R1: phase-1 gather fully coalesced (float2/lane) + 2 ds_bpermute per row.
// R2: phase-2 cross-lane shifts via DPP wave_shr/shl (register-only).
// R3: phase-2 LDS layout flipped to column-major k-indexed tables
//     Ftab[col][k=t-1], Btab[col][k=255-t], stride 130 (2-way bank alias =
//     free, float2-aligned). 5 scalar reads/iter -> 10 ds_read_b64 per
//     4-iteration group, prefetched one group ahead so the ~120cy LDS
//     latency hides under the f64 compute (1 wave/SIMD in phase 2 = no TLP
//     to hide it otherwise; rocprof showed ~640cy/iter = serialized lgkm).
//     t=0 init values live at Ftab[col][127]; tb=128 final step = Btab k=127.

#define CTC_B 1024
#define CTC_T 256
#define CTC_C 128
#define CTC_L 32
#define CTC_BLANK 127
#define CTC_EPS 1e-7f

#define KSTRIDE 130          // 128 k-slots + 2 pad -> 2-way bank alias (free)
#define TABSZ  (34 * KSTRIDE)

#define DPP_WAVE_SHL1 0x130  // lane i <- lane i+1, lane 63 <- 0 (bound_ctrl)
#define DPP_WAVE_SHR1 0x138  // lane i <- lane i-1, lane 0  <- 0 (bound_ctrl)

__device__ __forceinline__ double bperm_f64(int addr, double v) {
    union { double d; int i[2]; } u; u.d = v;
    int x = __builtin_amdgcn_ds_bpermute(addr, u.i[0]);
    int y = __builtin_amdgcn_ds_bpermute(addr, u.i[1]);
    union { int i[2]; double d; } r; r.i[0] = x; r.i[1] = y;
    return r.d;
}

__device__ __forceinline__ double dpp_shr1_f64(double v) {
    union { double d; int i[2]; } u; u.d = v;
    int x = __builtin_amdgcn_update_dpp(0, u.i[0], DPP_WAVE_SHR1, 0xF, 0xF, true);
    int y = __builtin_amdgcn_update_dpp(0, u.i[1], DPP_WAVE_SHR1, 0xF, 0xF, true);
    union { int i[2]; double d; } r; r.i[0] = x; r.i[1] = y;
    return r.d;
}

__device__ __forceinline__ double dpp_shl1_f64(double v) {
    union { double d; int i[2]; } u; u.d = v;
    int x = __builtin_amdgcn_update_dpp(0, u.i[0], DPP_WAVE_SHL1, 0xF, 0xF, true);
    int y = __builtin_amdgcn_update_dpp(0, u.i[1], DPP_WAVE_SHL1, 0xF, 0xF, true);
    union { int i[2]; double d; } r; r.i[0] = x; r.i[1] = y;
    return r.d;
}

__device__ __forceinline__ double bcast0_f64(double v) {
    union { double d; int i[2]; } u; u.d = v;
    int x = __builtin_amdgcn_readfirstlane(u.i[0]);
    int y = __builtin_amdgcn_readfirstlane(u.i[1]);
    union { int i[2]; double d; } r; r.i[0] = x; r.i[1] = y;
    return r.d;
}

__global__ __launch_bounds__(256) void ctc_loss_kernel(
    const int* __restrict__ y_true,   // [B, L] int32
    const float* __restrict__ y_pred, // [B, T, C] float32
    float* __restrict__ out)          // [B, 1] float32
{
    __shared__ float tabs[2 * TABSZ];   // 35.4 KB -> 4 blocks/CU
    float* Ftab = tabs;                 // [col][k], k = (t-1)&127  (t=0..127)
    float* Btab = tabs + TABSZ;         // [col][k], k = 255-t      (t=128..255)

    const int b = blockIdx.x;
    const int tid = threadIdx.x;
    const int lane = tid & 63;
    const int wave = tid >> 6;

    const float* yp = y_pred + (size_t)b * CTC_T * CTC_C;

    // per-lane gather label: lanes 0..31 -> y_true, others -> blank
    int lbl = CTC_BLANK;
    if (lane < CTC_L) lbl = y_true[b * CTC_L + lane];

    // ---- phase 1: wave w fills t in [w*64, w*64+64); col 33 = 0 ----
    // Coalesced: lane holds cols [2*lane, 2*lane+1] of row t; column lbl
    // lives in lane (lbl>>1), component (lbl&1). Pull via ds_bpermute.
    // Waves 0-1 (t<=127) write Ftab[lane][(t-1)&127]; waves 2-3 write
    // Btab[lane][255-t]. Lane-write stride 130 words -> 2-way alias (free).
    {
        const int t0 = wave * 64;
        const int src_addr = (lbl >> 1) << 2;   // byte addr of source lane
        const bool odd = (lbl & 1) != 0;
        float* tab = (wave < 2) ? Ftab : Btab;
        #pragma unroll 8
        for (int k = 0; k < 64; ++k) {
            const int t = t0 + k;
            const float2 r =
                *reinterpret_cast<const float2*>(yp + (size_t)t * CTC_C + 2 * lane);
            union { float f; int i; } c0, c1;
            c0.f = r.x; c1.f = r.y;
            int g0 = __builtin_amdgcn_ds_bpermute(src_addr, c0.i);
            int g1 = __builtin_amdgcn_ds_bpermute(src_addr, c1.i);
            union { int i; float f; } s0, s1;
            s0.i = g0; s1.i = g1;
            float p = odd ? s1.f : s0.f;
            float v = (lane == 33) ? 0.0f : (p + CTC_EPS) * 128.0f;
            const int idx = (wave < 2) ? ((t + 127) & 127) : (255 - t);
            if (lane <= 33) tab[lane * KSTRIDE + idx] = v;
        }
    }
    __syncthreads();

    if (wave != 0) return;

    // ---- per-lane constants ----
    double skip = 0.0;
    if (lane >= 1 && lane < CTC_L) {
        if (y_true[b * CTC_L + lane - 1] != lbl) skip = 1.0;
    }
    double skipn = 0.0;
    if (lane <= 30) {
        if (y_true[b * CTC_L + lane + 1] != lbl) skipn = 1.0;
    } else if (lane == 32) {
        skipn = 1.0;   // reuse v-term as the 0 -> 1 transition
    }

    const int lidx = (lane < 32) ? lane : 32;          // own label slot
    const int pv_idx = (lane < 32) ? lane : 33;        // fwd label (0 if dead)
    const int tn = (lane <= 30) ? (lane + 1)
                 : (lane == 31) ? 33                    // state 65: killed
                 : (lane == 32) ? 0                     // beta[0] uses p[1]
                 : 32;                                  // dead: harmless
    const int pbi = (lane == 32) ? 33 : 32;            // bwd blank (0 @ 32)
    const bool is32 = (lane == 32);

    // per-lane base pointers into the k-indexed tables
    const float* Fpv = Ftab + pv_idx * KSTRIDE;
    const float* Fpb = Ftab + 32 * KSTRIDE;
    const float* Bpa = Btab + lidx * KSTRIDE;
    const float* Bp1 = Btab + tn * KSTRIDE;
    const float* Bpb = Btab + pbi * KSTRIDE;

    // ---- init ---- (t=0 row lives at Ftab[col][127])
    double lo = 0.0, hi = 0.0;
    if (lane == 0) {
        lo = (double)Ftab[32 * KSTRIDE + 127];   // alpha[0] = blank @ t=0
        hi = (double)Ftab[0 * KSTRIDE + 127];    // alpha[1] = label0 @ t=0
    }
    double a = 0.0, bb = 0.0;
    if (lane == 31) { a = 1.0; bb = 1.0; }       // beta_255[63] = beta_255[64] = 1

#define STEP(pvf, pbf, paf, pa1f, pbbf) {                       \
        double ph  = dpp_shr1_f64(hi);                          \
        double a1s = dpp_shl1_f64(a);                           \
        double a1  = is32 ? bcast0_f64(a) : a1s;                \
        double nl = (lo + ph) * (double)(pbf);                  \
        double nh = (hi + lo + skip * ph) * (double)(pvf);      \
        double v  = (double)(pa1f) * a1;                        \
        double u  = (double)(pbbf) * bb;                        \
        double nb = u + v;                                      \
        double na = fma((double)(paf), a, fma(skipn, v, u));    \
        lo = nl; hi = nh; a = na; bb = nb;                      \
    }

#define LD2(p, o) (*reinterpret_cast<const float2*>((p) + (o)))

    // ---- 127 interleaved iterations (fwd t=1+k, bwd t=255-k), grouped by 4
    // with one-group-ahead prefetch. Group g covers k = 4g..4g+3.
    // Group 31: k=124..126 fwd+bwd; k=127 slot feeds the final bwd-only step
    // (Btab k=127 == tb=128) -- its Ftab k=127 load (t=0 row) is dead.
    float2 c_pv0 = LD2(Fpv, 0), c_pv1 = LD2(Fpv, 2);
    float2 c_pb0 = LD2(Fpb, 0), c_pb1 = LD2(Fpb, 2);
    float2 c_pa0 = LD2(Bpa, 0), c_pa1 = LD2(Bpa, 2);
    float2 c_p10 = LD2(Bp1, 0), c_p11 = LD2(Bp1, 2);
    float2 c_pb0b = LD2(Bpb, 0), c_pb1b = LD2(Bpb, 2);

    for (int g = 0; g < 31; ++g) {
        const int o = 4 * (g + 1);
        // prefetch group g+1 (independent of current compute)
        float2 n_pv0 = LD2(Fpv, o), n_pv1 = LD2(Fpv, o + 2);
        float2 n_pb0 = LD2(Fpb, o), n_pb1 = LD2(Fpb, o + 2);
        float2 n_pa0 = LD2(Bpa, o), n_pa1 = LD2(Bpa, o + 2);
        float2 n_p10 = LD2(Bp1, o), n_p11 = LD2(Bp1, o + 2);
        float2 n_pb0b = LD2(Bpb, o), n_pb1b = LD2(Bpb, o + 2);

        STEP(c_pv0.x, c_pb0.x, c_pa0.x, c_p10.x, c_pb0b.x);
        STEP(c_pv0.y, c_pb0.y, c_pa0.y, c_p10.y, c_pb0b.y);
        STEP(c_pv1.x, c_pb1.x, c_pa1.x, c_p11.x, c_pb1b.x);
        STEP(c_pv1.y, c_pb1.y, c_pa1.y, c_p11.y, c_pb1b.y);

        c_pv0 = n_pv0; c_pv1 = n_pv1;
        c_pb0 = n_pb0; c_pb1 = n_pb1;
        c_pa0 = n_pa0; c_pa1 = n_pa1;
        c_p10 = n_p10; c_p11 = n_p11;
        c_pb0b = n_pb0b; c_pb1b = n_pb1b;
    }

    // tail: k = 124, 125, 126 (fwd+bwd)
    STEP(c_pv0.x, c_pb0.x, c_pa0.x, c_p10.x, c_pb0b.x);
    STEP(c_pv0.y, c_pb0.y, c_pa0.y, c_p10.y, c_pb0b.y);
    STEP(c_pv1.x, c_pb1.x, c_pa1.x, c_p11.x, c_pb1b.x);

    // ---- final backward-only step: tb = 128 (Btab k=127) -> beta_127 ----
    {
        double a1s = dpp_shl1_f64(a);
        double a1  = is32 ? bcast0_f64(a) : a1s;
        double v  = (double)c_p11.y * a1;
        double u  = (double)c_pb1b.y * bb;
        double nb = u + v;
        double na = fma((double)c_pa1.y, a, fma(skipn, v, u));
        a = na; bb = nb;
    }

#undef STEP
#undef LD2

    // ---- combine: P = sum_s alpha_127[s] * beta_127[s] ----
    // beta[2i]: i=0 -> a_32 (beta[0]); i>=1 -> bb_{i-1}
    double beA = bperm_f64(32 << 2, a);                      // all: a_32
    double beB = bperm_f64(((lane + 63) & 63) << 2, bb);     // bb_{i-1}
    double be = (lane == 0) ? beA : beB;
    double partial = (lane <= 32) ? (lo * be + hi * a) : 0.0;
    #pragma unroll
    for (int off = 32; off >= 1; off >>= 1)
        partial += __shfl_down(partial, off);
    if (lane == 0) {
        out[b] = (float)(1242.1197475634219 - log(partial)); // 256*ln(128)
    }
}

extern "C" void kernel_launch(void* const* d_in, const int* in_sizes, int n_in,
                              void* d_out, int out_size, void* d_ws, size_t ws_size,
                              hipStream_t stream) {
    const int*   y_true = (const int*)d_in[0];
    const float* y_pred = (const float*)d_in[1];
    float*       out    = (float*)d_out;

    ctc_loss_kernel<<<CTC_B, 256, 0, stream>>>(y_true, y_pred, out);
}